// Round 6
// baseline (474.642 us; speedup 1.0000x reference)
//
#include <hip/hip_runtime.h>
#include <hip/hip_bf16.h>

#define B_ 2
#define N_ 2048
#define DIM_ 512
#define H_ 4
#define DH_ 128
#define DHID_ 512
#define CH_ 64
#define NC_ 32
#define BH_ 8

typedef __bf16 bf16x8 __attribute__((ext_vector_type(8)));
typedef float f32x4 __attribute__((ext_vector_type(4)));

__device__ __forceinline__ f32x4 MFMA(bf16x8 a, bf16x8 b, f32x4 c) {
    return __builtin_amdgcn_mfma_f32_16x16x32_bf16(a, b, c, 0, 0, 0);
}
__device__ __forceinline__ bf16x8 ld8(const __bf16* p) { return *(const bf16x8*)p; }

__device__ __forceinline__ float sigmoidf_(float x) { return 1.0f / (1.0f + expf(-x)); }

// fast tanh-form GELU (max |err| vs exact-erf ~1e-3; absmax headroom 0.31)
__device__ __forceinline__ float gelu_f(float x) {
    float x2 = x * x;
    float u = x * fmaf(0.0713548163f, x2, 1.5957691216f);
    float E = __expf(u);
    float r = __builtin_amdgcn_rcpf(E + 1.0f);
    return x * (1.0f - r);
}
__device__ __forceinline__ void gelu_fg(float x, float& f, float& g) {
    float x2 = x * x;
    float u = x * fmaf(0.0713548163f, x2, 1.5957691216f);
    float E = __expf(u);
    float r = __builtin_amdgcn_rcpf(E + 1.0f);
    float omr = 1.0f - r;
    f = x * omr;
    float th = 1.0f - 2.0f * r;
    float ap = fmaf(0.1070322244f, x2, 0.7978845608f);
    g = fmaf(0.5f * x * (1.0f - th * th), ap, omr);
}

// ---------------------------------------------------------------- rms norm + bf16 copies + fused lr/gate
__global__ __launch_bounds__(256) void rms_kernel(
    const float* __restrict__ seq, const float* __restrict__ gs,
    const float* __restrict__ gr, const float* __restrict__ Wa,
    const float* __restrict__ ba, const float* __restrict__ Wg,
    float* __restrict__ xs,
    __bf16* __restrict__ xsb, __bf16* __restrict__ xrb,
    float* __restrict__ lrb, float* __restrict__ gateb)
{
    const int row = blockIdx.x;
    const int t = threadIdx.x;
    const int wave = t >> 6, lane = t & 63;
    const float* x = seq + (size_t)row * DIM_;
    float v0 = x[t], v1 = x[t + 256];
    float ss = v0 * v0 + v1 * v1;
#pragma unroll
    for (int off = 32; off; off >>= 1) ss += __shfl_xor(ss, off);
    __shared__ float red[4];
    __shared__ float red2[4][8];
    if (lane == 0) red[wave] = ss;
    __syncthreads();
    float tot = red[0] + red[1] + red[2] + red[3];
    float r = rsqrtf(tot * (1.0f / DIM_) + 1e-6f);
    size_t o = (size_t)row * DIM_;
    float a0 = v0 * r * gs[t], a1 = v1 * r * gs[t + 256];
    float b0 = v0 * r * gr[t], b1 = v1 * r * gr[t + 256];
    xs[o + t] = a0; xs[o + t + 256] = a1;
    xsb[o + t] = (__bf16)a0; xsb[o + t + 256] = (__bf16)a1;
    xrb[o + t] = (__bf16)b0; xrb[o + t + 256] = (__bf16)b1;
    float pa[4], pg[4];
#pragma unroll
    for (int h = 0; h < 4; ++h) {
        pa[h] = a0 * Wa[t * 4 + h] + a1 * Wa[(t + 256) * 4 + h];
        pg[h] = b0 * Wg[t * 4 + h] + b1 * Wg[(t + 256) * 4 + h];
    }
#pragma unroll
    for (int h = 0; h < 4; ++h)
#pragma unroll
        for (int off = 32; off; off >>= 1) {
            pa[h] += __shfl_xor(pa[h], off);
            pg[h] += __shfl_xor(pg[h], off);
        }
    if (lane == 0) {
#pragma unroll
        for (int h = 0; h < 4; ++h) {
            red2[wave][h] = pa[h];
            red2[wave][4 + h] = pg[h];
        }
    }
    __syncthreads();
    if (t < 8) {
        float s = red2[0][t] + red2[1][t] + red2[2][t] + red2[3][t];
        int b = row >> 11, n = row & 2047;
        if (t < 4) lrb[(size_t)(b * 4 + t) * N_ + n] = sigmoidf_(s + ba[t]);
        else gateb[(size_t)(b * 4 + (t - 4)) * N_ + n] = sigmoidf_(s);
    }
}

// ---------------------------------------------------------------- pooled + beta/alpha fused
__global__ __launch_bounds__(256) void ba_kernel(
    const float* __restrict__ xs, const float* __restrict__ Wm,
    const float* __restrict__ Wd, const float* __restrict__ bd,
    float* __restrict__ beta, float* __restrict__ alpha)
{
    const int b = blockIdx.x >> 5, ci = blockIdx.x & 31;
    const int t = threadIdx.x;
    const int wave = t >> 6, lane = t & 63;
    const float* base = xs + ((size_t)b * N_ + ci * CH_) * DIM_;
    const int d0 = t * 2;
    float s0 = 0.f, s1 = 0.f;
#pragma unroll 8
    for (int r = 0; r < CH_; ++r) {
        s0 += base[(size_t)r * DIM_ + d0];
        s1 += base[(size_t)r * DIM_ + d0 + 1];
    }
    s0 *= (1.0f / CH_); s1 *= (1.0f / CH_);
    float pm[4], pd[4];
#pragma unroll
    for (int h = 0; h < 4; ++h) {
        pm[h] = s0 * Wm[d0 * 4 + h] + s1 * Wm[(d0 + 1) * 4 + h];
        pd[h] = s0 * Wd[d0 * 4 + h] + s1 * Wd[(d0 + 1) * 4 + h];
    }
#pragma unroll
    for (int h = 0; h < 4; ++h)
#pragma unroll
        for (int off = 32; off; off >>= 1) {
            pm[h] += __shfl_xor(pm[h], off);
            pd[h] += __shfl_xor(pd[h], off);
        }
    __shared__ float red2[4][8];
    if (lane == 0) {
#pragma unroll
        for (int h = 0; h < 4; ++h) {
            red2[wave][h] = pm[h];
            red2[wave][4 + h] = pd[h];
        }
    }
    __syncthreads();
    if (t < 4) {
        float sm = red2[0][t] + red2[1][t] + red2[2][t] + red2[3][t];
        float sd = red2[0][4 + t] + red2[1][4 + t] + red2[2][4 + t] + red2[3][4 + t];
        int bh = b * 4 + t;
        beta[bh * NC_ + ci] = sigmoidf_(sm);
        alpha[bh * NC_ + ci] = 1.0f - sigmoidf_(sd + bd[t]);
    }
}

// ---------------------------------------------------------------- weight prep: bf16 copies + transposes
__global__ __launch_bounds__(256) void prep_kernel(
    const float* __restrict__ w1, const float* __restrict__ w2,
    const float* __restrict__ Wq, const float* __restrict__ Wk,
    const float* __restrict__ Wv, const float* __restrict__ Wc,
    __bf16* __restrict__ w1b, __bf16* __restrict__ w1Tb,
    __bf16* __restrict__ w2b, __bf16* __restrict__ w2Tb,
    __bf16* __restrict__ WqT, __bf16* __restrict__ WkT,
    __bf16* __restrict__ WvT, __bf16* __restrict__ WcT)
{
    int idx = blockIdx.x * 256 + threadIdx.x;   // 262144
    if (idx < 65536) {
        w1b[idx] = (__bf16)w1[idx];                       // [d][j]
        int j = idx >> 7, d = idx & 127;
        w1Tb[idx] = (__bf16)w1[(size_t)d * DHID_ + j];    // [j][d]
        w2b[idx] = (__bf16)w2[idx];                       // [j][d]
        int d2 = idx >> 9, j2 = idx & 511;
        w2Tb[idx] = (__bf16)w2[(size_t)j2 * DH_ + d2];    // [d][j]
    }
    int n = idx >> 9, k = idx & 511;                      // WT[n][k] = W[k][n]
    WqT[idx] = (__bf16)Wq[(size_t)k * 512 + n];
    WkT[idx] = (__bf16)Wk[(size_t)k * 512 + n];
    WvT[idx] = (__bf16)Wv[(size_t)k * 512 + n];
    WcT[idx] = (__bf16)Wc[(size_t)k * 512 + n];
}

// ---------------------------------------------------------------- projections q/k/v
__global__ __launch_bounds__(256, 4) void proj_kernel(
    const __bf16* __restrict__ xsb, const __bf16* __restrict__ xrb,
    const __bf16* __restrict__ WqT, const __bf16* __restrict__ WkT,
    const __bf16* __restrict__ WvT,
    float* __restrict__ qb, float* __restrict__ kb, float* __restrict__ vb)
{
    const int z = blockIdx.z;
    const __bf16* A = (z == 0) ? xrb : xsb;
    const __bf16* WT = (z == 0) ? WqT : (z == 1 ? WkT : WvT);
    float* out = (z == 0) ? qb : (z == 1 ? kb : vb);
    const int t = threadIdx.x;
    const int wave = t >> 6, lane = t & 63;
    const int lrow = lane & 15, lgrp = lane >> 4;
    const int c0 = blockIdx.x * 64 + wave * 16;
    const int col0 = blockIdx.y * 64;
    f32x4 acc[4];
#pragma unroll
    for (int i = 0; i < 4; ++i) acc[i] = (f32x4)0.f;
    const __bf16* ar = A + (size_t)(c0 + lrow) * 512;
#pragma unroll 4
    for (int k0 = 0; k0 < 512; k0 += 32) {
        bf16x8 av = ld8(ar + k0 + lgrp * 8);
#pragma unroll
        for (int ct = 0; ct < 4; ++ct) {
            bf16x8 bv = ld8(WT + (size_t)(col0 + ct * 16 + lrow) * 512 + k0 + lgrp * 8);
            acc[ct] = MFMA(av, bv, acc[ct]);
        }
    }
#pragma unroll
    for (int ct = 0; ct < 4; ++ct)
#pragma unroll
        for (int r = 0; r < 4; ++r) {
            int row = c0 + lgrp * 4 + r, col = col0 + ct * 16 + lrow;
            int b = row >> 11, n = row & 2047, h = col >> 7, d = col & 127;
            out[((((size_t)(b * H_ + h) * NC_ + (n >> 6)) * CH_) + (n & 63)) * DH_ + d] = acc[ct][r];
        }
}

// ---------------------------------------------------------------- final combine GEMM
__global__ __launch_bounds__(256, 4) void gemm_out(
    const __bf16* __restrict__ A, const __bf16* __restrict__ WT, float* __restrict__ out)
{
    const int t = threadIdx.x;
    const int wave = t >> 6, lane = t & 63;
    const int lrow = lane & 15, lgrp = lane >> 4;
    const int c0 = blockIdx.x * 64 + wave * 16;
    const int col0 = blockIdx.y * 64;
    f32x4 acc[4];
#pragma unroll
    for (int i = 0; i < 4; ++i) acc[i] = (f32x4)0.f;
    const __bf16* ar = A + (size_t)(c0 + lrow) * 512;
#pragma unroll 4
    for (int k0 = 0; k0 < 512; k0 += 32) {
        bf16x8 av = ld8(ar + k0 + lgrp * 8);
#pragma unroll
        for (int ct = 0; ct < 4; ++ct) {
            bf16x8 bv = ld8(WT + (size_t)(col0 + ct * 16 + lrow) * 512 + k0 + lgrp * 8);
            acc[ct] = MFMA(av, bv, acc[ct]);
        }
    }
#pragma unroll
    for (int ct = 0; ct < 4; ++ct)
#pragma unroll
        for (int r = 0; r < 4; ++r) {
            int row = c0 + lgrp * 4 + r, col = col0 + ct * 16 + lrow;
            out[(size_t)row * 512 + col] = acc[ct][r];
        }
}

// ---------------------------------------------------------------- hprep: rms(k) -> hb [blk][c][d], hTb [blk][d][c]
__global__ __launch_bounds__(256) void hprep_kernel(
    const float* __restrict__ kbuf, const float* __restrict__ memg,
    __bf16* __restrict__ hb, __bf16* __restrict__ hTb)
{
    const int blk = blockIdx.x;
    const int t = threadIdx.x;
    __shared__ __bf16 h_s[64][130];
    __shared__ float g_s[128];
    if (t < 128) g_s[t] = memg[t];
    const int c = t >> 2, q = t & 3, d0 = q * 32;
    const float* kc = kbuf + (size_t)blk * 8192 + (size_t)c * 128 + d0;
    float xv[32];
    float ss = 0.f;
#pragma unroll
    for (int i = 0; i < 8; ++i) {
        float4 f = *(const float4*)(kc + i * 4);
        xv[i * 4 + 0] = f.x; xv[i * 4 + 1] = f.y; xv[i * 4 + 2] = f.z; xv[i * 4 + 3] = f.w;
        ss += f.x * f.x + f.y * f.y + f.z * f.z + f.w * f.w;
    }
    ss += __shfl_xor(ss, 1); ss += __shfl_xor(ss, 2);
    float r = rsqrtf(ss * (1.0f / DH_) + 1e-6f);
    __syncthreads();   // g_s
    bf16x8 pk[4];
#pragma unroll
    for (int i = 0; i < 32; ++i) {
        __bf16 hv = (__bf16)(xv[i] * r * g_s[d0 + i]);
        h_s[c][d0 + i] = hv;
        pk[i >> 3][i & 7] = hv;
    }
    __bf16* hrow = hb + (size_t)blk * 8192 + (size_t)c * 128 + d0;
#pragma unroll
    for (int i = 0; i < 4; ++i) *(bf16x8*)(hrow + i * 8) = pk[i];
    __syncthreads();
    const int d = t >> 1, c0 = (t & 1) * 32;
#pragma unroll
    for (int i = 0; i < 4; ++i) {
        bf16x8 o;
#pragma unroll
        for (int k = 0; k < 8; ++k) o[k] = h_s[c0 + i * 8 + k][d];
        *(bf16x8*)(hTb + (size_t)blk * 8192 + (size_t)d * 64 + c0 + i * 8) = o;
    }
}

// ---------------------------------------------------------------- grad fwd: e = lr*2/DH*(mlp(h)+k-v)
// grid 512: (chunk, c-half 32). 16 waves. z: (c-strip 16 x j-64); y: (c-strip 16 x d-16, K=512)
__global__ __launch_bounds__(1024, 8) void gradfwd_kernel(
    const __bf16* __restrict__ hb, const float* __restrict__ kbuf,
    const float* __restrict__ vbuf, const float* __restrict__ lrbuf,
    const __bf16* __restrict__ w1Tb, const __bf16* __restrict__ w2Tb,
    __bf16* __restrict__ eb, __bf16* __restrict__ eTb)
{
    const int bi = blockIdx.x;
    const int blk = bi >> 1, chalf = bi & 1;
    const int t = threadIdx.x;
    const int w = t >> 6, lane = t & 63;
    const int lrow = lane & 15, lgrp = lane >> 4;
    const int bh = blk >> 5, nc = blk & 31;

    __shared__ __bf16 a_s[32][516];
    __shared__ float lr_s[32];
    if (t < 32) lr_s[t] = lrbuf[(size_t)bh * N_ + nc * CH_ + chalf * 32 + t];

    const __bf16* hblk = hb + (size_t)blk * 8192 + (size_t)chalf * 32 * 128;

    // ---- z = h @ w1, a = gelu(z) ----
    {
        const int cs = w & 1, jq = w >> 1;
        const int j0 = jq * 64;
        f32x4 zacc[4];
#pragma unroll
        for (int i = 0; i < 4; ++i) zacc[i] = (f32x4)0.f;
#pragma unroll
        for (int kt = 0; kt < 4; ++kt) {
            bf16x8 av = ld8(hblk + (size_t)(cs * 16 + lrow) * 128 + kt * 32 + lgrp * 8);
#pragma unroll
            for (int ct = 0; ct < 4; ++ct) {
                bf16x8 bv = ld8(w1Tb + (size_t)(j0 + ct * 16 + lrow) * 128 + kt * 32 + lgrp * 8);
                zacc[ct] = MFMA(av, bv, zacc[ct]);
            }
        }
#pragma unroll
        for (int ct = 0; ct < 4; ++ct)
#pragma unroll
            for (int r = 0; r < 4; ++r)
                a_s[cs * 16 + lgrp * 4 + r][j0 + ct * 16 + lrow] = (__bf16)gelu_f(zacc[ct][r]);
    }
    __syncthreads();

    // ---- y = a @ w2 (K=512), e epilogue ----
    {
        const int cs = w & 1, dq = w >> 1;
        const int d0 = dq * 16;
        f32x4 yacc = (f32x4)0.f;
#pragma unroll
        for (int kt = 0; kt < 16; ++kt) {
            bf16x8 av = ld8(&a_s[cs * 16 + lrow][kt * 32 + lgrp * 8]);
            bf16x8 bv = ld8(w2Tb + (size_t)(d0 + lrow) * 512 + kt * 32 + lgrp * 8);
            yacc = MFMA(av, bv, yacc);
        }
        const int d = d0 + lrow;
#pragma unroll
        for (int r = 0; r < 4; ++r) {
            int cl = cs * 16 + lgrp * 4 + r;             // 0..31
            int cc = chalf * 32 + cl;                    // 0..63 within chunk
            float kv = kbuf[(size_t)blk * 8192 + (size_t)cc * 128 + d];
            float vv = vbuf[(size_t)blk * 8192 + (size_t)cc * 128 + d];
            float e = lr_s[cl] * (2.0f / DH_) * (yacc[r] + kv - vv);
            eb[(size_t)blk * 8192 + (size_t)cc * 128 + d] = (__bf16)e;
            eTb[(size_t)blk * 8192 + (size_t)d * 64 + cc] = (__bf16)e;
        }
    }
}

// ---------------------------------------------------------------- grad bwd: sw1 = -dzT@hT, sw2 = -eT@aT, dg fused
// grid 512: (chunk, j-half). 16 waves: js = w&7 (j-strip 16 of 128), chh = w>>3 (c/d/j half)
__global__ __launch_bounds__(1024, 8) void gradbwd_kernel(
    const __bf16* __restrict__ hb, const __bf16* __restrict__ hTb,
    const __bf16* __restrict__ eb, const __bf16* __restrict__ eTb,
    const __bf16* __restrict__ w1b, const __bf16* __restrict__ w1Tb,
    const __bf16* __restrict__ w2b,
    __bf16* __restrict__ sw1, __bf16* __restrict__ sw2,
    float* __restrict__ sgpA, float* __restrict__ sgpB)
{
    const int bi = blockIdx.x;
    const int blk = bi >> 1, jhalf = bi & 1;
    const int t = threadIdx.x;
    const int w = t >> 6, lane = t & 63;
    const int lrow = lane & 15, lgrp = lane >> 4;
    const int js = w & 7, chh = w >> 3;
    const __bf16* hblk = hb + (size_t)blk * 8192;
    const __bf16* eblk = eb + (size_t)blk * 8192;
    const __bf16* hTblk = hTb + (size_t)blk * 8192;
    const __bf16* eTblk = eTb + (size_t)blk * 8192;
    __bf16* sw1_blk = sw1 + (size_t)blk * (DHID_ * DH_);
    __bf16* sw2_blk = sw2 + (size_t)blk * (DHID_ * DH_);

    __shared__ __bf16 aT_s[128][66];
    __shared__ __bf16 dzT_s[128][66];
    __shared__ float part_dg[16][64];

    float dgacc[4] = {0.f, 0.f, 0.f, 0.f};

    for (int jt = jhalf * 2; jt < jhalf * 2 + 2; ++jt) {
        const int jg0 = jt * 128;
        // zT[j][c] = w1T @ h ; daT[j][c] = w2 @ e   (K=d)
        f32x4 ztacc[2], dtacc[2];
        ztacc[0] = (f32x4)0.f; ztacc[1] = (f32x4)0.f;
        dtacc[0] = (f32x4)0.f; dtacc[1] = (f32x4)0.f;
#pragma unroll
        for (int kt = 0; kt < 4; ++kt) {
            bf16x8 avz = ld8(w1Tb + (size_t)(jg0 + js * 16 + lrow) * 128 + kt * 32 + lgrp * 8);
            bf16x8 avd = ld8(w2b + (size_t)(jg0 + js * 16 + lrow) * 128 + kt * 32 + lgrp * 8);
#pragma unroll
            for (int ct = 0; ct < 2; ++ct) {
                bf16x8 bvh = ld8(hblk + (size_t)(chh * 32 + ct * 16 + lrow) * 128 + kt * 32 + lgrp * 8);
                bf16x8 bve = ld8(eblk + (size_t)(chh * 32 + ct * 16 + lrow) * 128 + kt * 32 + lgrp * 8);
                ztacc[ct] = MFMA(avz, bvh, ztacc[ct]);
                dtacc[ct] = MFMA(avd, bve, dtacc[ct]);
            }
        }
#pragma unroll
        for (int ct = 0; ct < 2; ++ct)
#pragma unroll
            for (int r = 0; r < 4; ++r) {
                int jl = js * 16 + lgrp * 4 + r, c = chh * 32 + ct * 16 + lrow;
                float gf, gg;
                gelu_fg(ztacc[ct][r], gf, gg);
                aT_s[jl][c] = (__bf16)gf;
                dzT_s[jl][c] = (__bf16)(dtacc[ct][r] * gg);
            }
        __syncthreads();
        // dw1T[j-strip][d-half] = dzT @ hT (K=c); fused dg
        {
            f32x4 wacc[4];
#pragma unroll
            for (int i = 0; i < 4; ++i) wacc[i] = (f32x4)0.f;
#pragma unroll
            for (int kt = 0; kt < 2; ++kt) {
                bf16x8 av = ld8(&dzT_s[js * 16 + lrow][kt * 32 + lgrp * 8]);
#pragma unroll
                for (int ct = 0; ct < 4; ++ct) {
                    bf16x8 bv = ld8(hTblk + (size_t)(chh * 64 + ct * 16 + lrow) * 64 + kt * 32 + lgrp * 8);
                    wacc[ct] = MFMA(av, bv, wacc[ct]);
                }
            }
#pragma unroll
            for (int ct = 0; ct < 4; ++ct) {
                int d = chh * 64 + ct * 16 + lrow;
#pragma unroll
                for (int r = 0; r < 4; ++r) {
                    int jg = jg0 + js * 16 + lgrp * 4 + r;
                    sw1_blk[(size_t)jg * 128 + d] = (__bf16)(-wacc[ct][r]);
                    // dg[d] -= w1[d][j] * G1[j][d]   (w1Tb[j][d] = w1[d][j])
                    dgacc[ct] -= (float)w1Tb[(size_t)jg * 128 + d] * wacc[ct][r];
                }
            }
        }
        // dw2T[d-strip][j-half] = eT @ aT (K=c)
        {
            f32x4 wacc[4];
#pragma unroll
            for (int i = 0; i < 4; ++i) wacc[i] = (f32x4)0.f;
#pragma unroll
            for (int kt = 0; kt < 2; ++kt) {
                bf16x8 av = ld8(eTblk + (size_t)(js * 16 + lrow) * 64 + kt * 32 + lgrp * 8);
#pragma unroll
                for (int ct = 0; ct < 4; ++ct) {
                    bf16x8 bv = ld8(&aT_s[chh * 64 + ct * 16 + lrow][kt * 32 + lgrp * 8]);
                    wacc[ct] = MFMA(av, bv, wacc[ct]);
                }
            }
#pragma unroll
            for (int ct = 0; ct < 4; ++ct)
#pragma unroll
                for (int r = 0; r < 4; ++r) {
                    int d = js * 16 + lgrp * 4 + r, jg = jg0 + chh * 64 + ct * 16 + lrow;
                    sw2_blk[(size_t)d * 512 + jg] = (__bf16)(-wacc[ct][r]);
                }
        }
        __syncthreads();
    }
    // dg reduce: sum over lgrp (j-subgroups), then over js waves
#pragma unroll
    for (int ct = 0; ct < 4; ++ct) {
        dgacc[ct] += __shfl_xor(dgacc[ct], 16);
        dgacc[ct] += __shfl_xor(dgacc[ct], 32);
    }
    if (lane < 16) {
#pragma unroll
        for (int ct = 0; ct < 4; ++ct) part_dg[w][ct * 16 + lane] = dgacc[ct];
    }
    __syncthreads();
    if (t < 128) {
        int grp = t >> 6;     // which d-half -> chh group
        float s = 0.f;
#pragma unroll
        for (int j = 0; j < 8; ++j) s += part_dg[grp * 8 + j][t & 63];
        float* dst = jhalf ? sgpB : sgpA;
        dst[(size_t)blk * DH_ + t] = s;
    }
}

// ---------------------------------------------------------------- all scans, one launch (bf16x8 vectorized)
__global__ __launch_bounds__(256) void scan_all(
    __bf16* __restrict__ sw1, const __bf16* __restrict__ w1T,
    __bf16* __restrict__ sw2, const __bf16* __restrict__ w2T,
    float* __restrict__ sgb, const float* __restrict__ sgpB,
    const float* __restrict__ memg,
    const float* __restrict__ beta, const float* __restrict__ alpha)
{
    const int bi = blockIdx.x, t = threadIdx.x;
    if (bi < 512) {
        __bf16* buf = (bi < 256) ? sw1 : sw2;
        const __bf16* init = (bi < 256) ? w1T : w2T;
        int idx = (bi & 255) * 256 + t;          // 0..65535
        int bh = idx >> 13, e8 = idx & 8191;
        size_t off = (size_t)e8 * 8;
        const float* bp = beta + bh * NC_;
        const float* ap = alpha + bh * NC_;
        __bf16* base = buf + (size_t)bh * NC_ * 65536 + off;
        bf16x8 iv = *(const bf16x8*)(init + off);
        float m[8], wv[8];
#pragma unroll
        for (int k = 0; k < 8; ++k) { m[k] = 0.f; wv[k] = (float)iv[k]; }
        for (int ci = 0; ci < NC_; ++ci) {
            bf16x8 s = *(const bf16x8*)(base + (size_t)ci * 65536);
            float bb = bp[ci], aa = ap[ci];
            bf16x8 o;
#pragma unroll
            for (int k = 0; k < 8; ++k) {
                o[k] = (__bf16)wv[k];
                m[k] = fmaf(bb, m[k], (float)s[k]);
                wv[k] = fmaf(aa, wv[k], m[k]);
            }
            *(bf16x8*)(base + (size_t)ci * 65536) = o;
        }
    } else {
        int idx = (bi - 512) * 256 + t;   // < 1024
        int bh = idx >> 7, el = idx & 127;
        float g = memg[el];
        float rg = 1.0f / g;
        float wv = g, m = 0.f;
        const float* bp = beta + bh * NC_;
        const float* ap = alpha + bh * NC_;
        float* base = sgb + ((size_t)bh * NC_) * 128 + el;
        const float* baseB = sgpB + ((size_t)bh * NC_) * 128 + el;
        for (int ci = 0; ci < NC_; ++ci) {
            float s = (base[(size_t)ci * 128] + baseB[(size_t)ci * 128]) * rg;
            base[(size_t)ci * 128] = wv;
            m = fmaf(bp[ci], m, s);
            wv = fmaf(ap[ci], wv, m);
        }
    }
}

// ---------------------------------------------------------------- retrieval (MFMA forward, 8 waves) + gate
__global__ __launch_bounds__(512, 4) void retrieve_kernel(
    const float* __restrict__ qbuf, const float* __restrict__ gatebuf,
    const float* __restrict__ sg, const __bf16* __restrict__ sw1,
    const __bf16* __restrict__ sw2, __bf16* __restrict__ retgb)
{
    const int blk = blockIdx.x;
    const int t = threadIdx.x;
    const int w = t >> 6, lane = t & 63;
    const int lrow = lane & 15, lgrp = lane >> 4;
    const int bh = blk >> 5, nc = blk & 31;
    const float* qc = qbuf + (size_t)blk * (CH_ * DH_);
    const __bf16* w1p = sw1 + (size_t)blk * (DHID_ * DH_);
    const __bf16* w2p = sw2 + (size_t)blk * (DHID_ * DH_);
    const float* gp = sg + (size_t)blk * DH_;

    __shared__ __bf16 h_s[64][136];
    __shared__ __bf16 a_s[64][136];
    __shared__ float g_s[128];

    if (t < 128) g_s[t] = gp[t];
    {
        const int c = t >> 3, dblk = t & 7, d0 = dblk * 16;
        float xv[16];
        float ss = 0.f;
#pragma unroll
        for (int i = 0; i < 4; ++i) {
            float4 f = *(const float4*)(qc + (size_t)c * DH_ + d0 + i * 4);
            xv[i * 4 + 0] = f.x; xv[i * 4 + 1] = f.y; xv[i * 4 + 2] = f.z; xv[i * 4 + 3] = f.w;
            ss += f.x * f.x + f.y * f.y + f.z * f.z + f.w * f.w;
        }
        ss += __shfl_xor(ss, 1); ss += __shfl_xor(ss, 2); ss += __shfl_xor(ss, 4);
        float r = rsqrtf(ss * (1.0f / DH_) + 1e-6f);
        __syncthreads();   // g_s visible
#pragma unroll
        for (int i = 0; i < 16; ++i)
            h_s[c][d0 + i] = (__bf16)(xv[i] * r * g_s[d0 + i]);
    }
    __syncthreads();

    const int cs = w & 3, dh2 = w >> 2;
    const int c0w = cs * 16, d0w = dh2 * 64;
    f32x4 yacc[4];
#pragma unroll
    for (int i = 0; i < 4; ++i) yacc[i] = (f32x4)0.f;

    for (int jt = 0; jt < 4; ++jt) {
        f32x4 zacc[4];
#pragma unroll
        for (int i = 0; i < 4; ++i) zacc[i] = (f32x4)0.f;
#pragma unroll
        for (int kt = 0; kt < 4; ++kt) {
            bf16x8 av = ld8(&h_s[c0w + lrow][kt * 32 + lgrp * 8]);
#pragma unroll
            for (int ct = 0; ct < 4; ++ct) {
                int j = jt * 128 + d0w + ct * 16 + lrow;
                bf16x8 bv = ld8(w1p + (size_t)j * 128 + kt * 32 + lgrp * 8);
                zacc[ct] = MFMA(av, bv, zacc[ct]);
            }
        }
#pragma unroll
        for (int ct = 0; ct < 4; ++ct)
#pragma unroll
            for (int r = 0; r < 4; ++r)
                a_s[c0w + lgrp * 4 + r][d0w + ct * 16 + lrow] = (__bf16)gelu_f(zacc[ct][r]);
        __syncthreads();
#pragma unroll
        for (int kt = 0; kt < 4; ++kt) {
            bf16x8 av = ld8(&a_s[c0w + lrow][kt * 32 + lgrp * 8]);
#pragma unroll
            for (int ct = 0; ct < 4; ++ct) {
                int d = d0w + ct * 16 + lrow;
                bf16x8 bv = ld8(w2p + (size_t)d * 512 + jt * 128 + kt * 32 + lgrp * 8);
                yacc[ct] = MFMA(av, bv, yacc[ct]);
            }
        }
        __syncthreads();
    }
    const int b = bh >> 2, hh = bh & 3;
#pragma unroll
    for (int ct = 0; ct < 4; ++ct)
#pragma unroll
        for (int r = 0; r < 4; ++r) {
            int c = c0w + lgrp * 4 + r, d = d0w + ct * 16 + lrow;
            int n = nc * CH_ + c;
            float q = qc[(size_t)c * DH_ + d];
            float gv = gatebuf[(size_t)bh * N_ + n];
            retgb[((size_t)(b * N_ + n)) * 512 + hh * 128 + d] = (__bf16)((yacc[ct][r] + q) * gv);
        }
}

// ---------------------------------------------------------------- launch
extern "C" void kernel_launch(void* const* d_in, const int* in_sizes, int n_in,
                              void* d_out, int out_size, void* d_ws, size_t ws_size,
                              hipStream_t stream) {
    const float* seq     = (const float*)d_in[0];
    const float* g_store = (const float*)d_in[1];
    const float* g_retr  = (const float*)d_in[2];
    const float* Wq = (const float*)d_in[3];
    const float* Wk = (const float*)d_in[4];
    const float* Wv = (const float*)d_in[5];
    const float* Wa = (const float*)d_in[6];
    const float* ba = (const float*)d_in[7];
    const float* Wm = (const float*)d_in[8];
    const float* Wd = (const float*)d_in[9];
    const float* bd = (const float*)d_in[10];
    const float* Wg = (const float*)d_in[11];
    const float* Wc = (const float*)d_in[12];
    const float* memg = (const float*)d_in[13];
    const float* w1 = (const float*)d_in[14];
    const float* w2 = (const float*)d_in[15];
    float* out = (float*)d_out;

    float* p = (float*)d_ws;
    float* xs = p;     p += (size_t)B_ * N_ * DIM_;
    float* kb = p;     p += (size_t)B_ * N_ * DIM_;
    float* vb = p;     p += (size_t)B_ * N_ * DIM_;
    float* qb = p;     p += (size_t)B_ * N_ * DIM_;
    float* lrb = p;    p += (size_t)BH_ * N_;
    float* gateb = p;  p += (size_t)BH_ * N_;
    float* beta = p;   p += BH_ * NC_;
    float* alpha = p;  p += BH_ * NC_;
    float* sgb = p;    p += (size_t)BH_ * NC_ * DH_;
    float* sgpB = p;   p += (size_t)BH_ * NC_ * DH_;

    __bf16* bp_ = (__bf16*)p;
    __bf16* xsb = bp_;  bp_ += (size_t)B_ * N_ * DIM_;
    __bf16* xrb = bp_;  bp_ += (size_t)B_ * N_ * DIM_;
    __bf16* retgb = bp_; bp_ += (size_t)B_ * N_ * DIM_;
    __bf16* hbuf = bp_; bp_ += (size_t)BH_ * N_ * DH_;
    __bf16* hTbuf = bp_; bp_ += (size_t)BH_ * N_ * DH_;
    __bf16* ebuf = bp_; bp_ += (size_t)BH_ * N_ * DH_;
    __bf16* eTbuf = bp_; bp_ += (size_t)BH_ * N_ * DH_;
    __bf16* w1b = bp_;  bp_ += DH_ * DHID_;
    __bf16* w1Tb = bp_; bp_ += DH_ * DHID_;
    __bf16* w2b = bp_;  bp_ += DH_ * DHID_;
    __bf16* w2Tb = bp_; bp_ += DH_ * DHID_;
    __bf16* WqT = bp_;  bp_ += DIM_ * DIM_;
    __bf16* WkT = bp_;  bp_ += DIM_ * DIM_;
    __bf16* WvT = bp_;  bp_ += DIM_ * DIM_;
    __bf16* WcT = bp_;  bp_ += DIM_ * DIM_;
    __bf16* sw1b = bp_; bp_ += (size_t)BH_ * NC_ * DH_ * DHID_;
    __bf16* sw2b = bp_; bp_ += (size_t)BH_ * NC_ * DH_ * DHID_;

    rms_kernel<<<B_ * N_, 256, 0, stream>>>(seq, g_store, g_retr, Wa, ba, Wg,
                                            xs, xsb, xrb, lrb, gateb);
    ba_kernel<<<B_ * NC_, 256, 0, stream>>>(xs, Wm, Wd, bd, beta, alpha);
    prep_kernel<<<1024, 256, 0, stream>>>(w1, w2, Wq, Wk, Wv, Wc,
                                          w1b, w1Tb, w2b, w2Tb, WqT, WkT, WvT, WcT);
    proj_kernel<<<dim3(64, 8, 3), 256, 0, stream>>>(xsb, xrb, WqT, WkT, WvT, qb, kb, vb);
    hprep_kernel<<<BH_ * NC_, 256, 0, stream>>>(kb, memg, hbuf, hTbuf);
    gradfwd_kernel<<<BH_ * NC_ * 2, 1024, 0, stream>>>(hbuf, kb, vb, lrb, w1Tb, w2Tb,
                                                       ebuf, eTbuf);
    gradbwd_kernel<<<BH_ * NC_ * 2, 1024, 0, stream>>>(hbuf, hTbuf, ebuf, eTbuf,
                                                       w1b, w1Tb, w2b,
                                                       sw1b, sw2b, sgb, sgpB);
    scan_all<<<516, 256, 0, stream>>>(sw1b, w1Tb, sw2b, w2Tb, sgb, sgpB, memg, beta, alpha);
    retrieve_kernel<<<BH_ * NC_, 512, 0, stream>>>(qb, gateb, sgb, sw1b, sw2b, retgb);
    gemm_out<<<dim3(64, 8), 256, 0, stream>>>(retgb, WcT, out);
}

// Round 8
// 321.643 us; speedup vs baseline: 1.4757x; 1.4757x over previous
//
#include <hip/hip_runtime.h>
#include <hip/hip_bf16.h>

#define B_ 2
#define N_ 2048
#define DIM_ 512
#define H_ 4
#define DH_ 128
#define DHID_ 512
#define CH_ 64
#define NC_ 32
#define BH_ 8

typedef __bf16 bf16x8 __attribute__((ext_vector_type(8)));
typedef float f32x4 __attribute__((ext_vector_type(4)));

__device__ __forceinline__ f32x4 MFMA(bf16x8 a, bf16x8 b, f32x4 c) {
    return __builtin_amdgcn_mfma_f32_16x16x32_bf16(a, b, c, 0, 0, 0);
}
__device__ __forceinline__ bf16x8 ld8(const __bf16* p) { return *(const bf16x8*)p; }

__device__ __forceinline__ float sigmoidf_(float x) { return 1.0f / (1.0f + expf(-x)); }

// fast tanh-form GELU (max |err| vs exact-erf ~1e-3; absmax headroom 0.31)
__device__ __forceinline__ float gelu_f(float x) {
    float x2 = x * x;
    float u = x * fmaf(0.0713548163f, x2, 1.5957691216f);
    float E = __expf(u);
    float r = __builtin_amdgcn_rcpf(E + 1.0f);
    return x * (1.0f - r);
}
__device__ __forceinline__ void gelu_fg(float x, float& f, float& g) {
    float x2 = x * x;
    float u = x * fmaf(0.0713548163f, x2, 1.5957691216f);
    float E = __expf(u);
    float r = __builtin_amdgcn_rcpf(E + 1.0f);
    float omr = 1.0f - r;
    f = x * omr;
    float th = 1.0f - 2.0f * r;
    float ap = fmaf(0.1070322244f, x2, 0.7978845608f);
    g = fmaf(0.5f * x * (1.0f - th * th), ap, omr);
}

// ---------------------------------------------------------------- rms norm + bf16 copies + fused lr/gate
__global__ __launch_bounds__(256) void rms_kernel(
    const float* __restrict__ seq, const float* __restrict__ gs,
    const float* __restrict__ gr, const float* __restrict__ Wa,
    const float* __restrict__ ba, const float* __restrict__ Wg,
    float* __restrict__ xs,
    __bf16* __restrict__ xsb, __bf16* __restrict__ xrb,
    float* __restrict__ lrb, float* __restrict__ gateb)
{
    const int row = blockIdx.x;
    const int t = threadIdx.x;
    const int wave = t >> 6, lane = t & 63;
    const float* x = seq + (size_t)row * DIM_;
    float v0 = x[t], v1 = x[t + 256];
    float ss = v0 * v0 + v1 * v1;
#pragma unroll
    for (int off = 32; off; off >>= 1) ss += __shfl_xor(ss, off);
    __shared__ float red[4];
    __shared__ float red2[4][8];
    if (lane == 0) red[wave] = ss;
    __syncthreads();
    float tot = red[0] + red[1] + red[2] + red[3];
    float r = rsqrtf(tot * (1.0f / DIM_) + 1e-6f);
    size_t o = (size_t)row * DIM_;
    float a0 = v0 * r * gs[t], a1 = v1 * r * gs[t + 256];
    float b0 = v0 * r * gr[t], b1 = v1 * r * gr[t + 256];
    xs[o + t] = a0; xs[o + t + 256] = a1;
    xsb[o + t] = (__bf16)a0; xsb[o + t + 256] = (__bf16)a1;
    xrb[o + t] = (__bf16)b0; xrb[o + t + 256] = (__bf16)b1;
    float pa[4], pg[4];
#pragma unroll
    for (int h = 0; h < 4; ++h) {
        pa[h] = a0 * Wa[t * 4 + h] + a1 * Wa[(t + 256) * 4 + h];
        pg[h] = b0 * Wg[t * 4 + h] + b1 * Wg[(t + 256) * 4 + h];
    }
#pragma unroll
    for (int h = 0; h < 4; ++h)
#pragma unroll
        for (int off = 32; off; off >>= 1) {
            pa[h] += __shfl_xor(pa[h], off);
            pg[h] += __shfl_xor(pg[h], off);
        }
    if (lane == 0) {
#pragma unroll
        for (int h = 0; h < 4; ++h) {
            red2[wave][h] = pa[h];
            red2[wave][4 + h] = pg[h];
        }
    }
    __syncthreads();
    if (t < 8) {
        float s = red2[0][t] + red2[1][t] + red2[2][t] + red2[3][t];
        int b = row >> 11, n = row & 2047;
        if (t < 4) lrb[(size_t)(b * 4 + t) * N_ + n] = sigmoidf_(s + ba[t]);
        else gateb[(size_t)(b * 4 + (t - 4)) * N_ + n] = sigmoidf_(s);
    }
}

// ---------------------------------------------------------------- pooled + beta/alpha fused
__global__ __launch_bounds__(256) void ba_kernel(
    const float* __restrict__ xs, const float* __restrict__ Wm,
    const float* __restrict__ Wd, const float* __restrict__ bd,
    float* __restrict__ beta, float* __restrict__ alpha)
{
    const int b = blockIdx.x >> 5, ci = blockIdx.x & 31;
    const int t = threadIdx.x;
    const int wave = t >> 6, lane = t & 63;
    const float* base = xs + ((size_t)b * N_ + ci * CH_) * DIM_;
    const int d0 = t * 2;
    float s0 = 0.f, s1 = 0.f;
#pragma unroll 8
    for (int r = 0; r < CH_; ++r) {
        s0 += base[(size_t)r * DIM_ + d0];
        s1 += base[(size_t)r * DIM_ + d0 + 1];
    }
    s0 *= (1.0f / CH_); s1 *= (1.0f / CH_);
    float pm[4], pd[4];
#pragma unroll
    for (int h = 0; h < 4; ++h) {
        pm[h] = s0 * Wm[d0 * 4 + h] + s1 * Wm[(d0 + 1) * 4 + h];
        pd[h] = s0 * Wd[d0 * 4 + h] + s1 * Wd[(d0 + 1) * 4 + h];
    }
#pragma unroll
    for (int h = 0; h < 4; ++h)
#pragma unroll
        for (int off = 32; off; off >>= 1) {
            pm[h] += __shfl_xor(pm[h], off);
            pd[h] += __shfl_xor(pd[h], off);
        }
    __shared__ float red2[4][8];
    if (lane == 0) {
#pragma unroll
        for (int h = 0; h < 4; ++h) {
            red2[wave][h] = pm[h];
            red2[wave][4 + h] = pd[h];
        }
    }
    __syncthreads();
    if (t < 4) {
        float sm = red2[0][t] + red2[1][t] + red2[2][t] + red2[3][t];
        float sd = red2[0][4 + t] + red2[1][4 + t] + red2[2][4 + t] + red2[3][4 + t];
        int bh = b * 4 + t;
        beta[bh * NC_ + ci] = sigmoidf_(sm);
        alpha[bh * NC_ + ci] = 1.0f - sigmoidf_(sd + bd[t]);
    }
}

// ---------------------------------------------------------------- weight prep: bf16 copies + transposes
__global__ __launch_bounds__(256) void prep_kernel(
    const float* __restrict__ w1, const float* __restrict__ w2,
    const float* __restrict__ Wq, const float* __restrict__ Wk,
    const float* __restrict__ Wv, const float* __restrict__ Wc,
    __bf16* __restrict__ w1b, __bf16* __restrict__ w1Tb,
    __bf16* __restrict__ w2b, __bf16* __restrict__ w2Tb,
    __bf16* __restrict__ WqT, __bf16* __restrict__ WkT,
    __bf16* __restrict__ WvT, __bf16* __restrict__ WcT)
{
    int idx = blockIdx.x * 256 + threadIdx.x;   // 262144
    if (idx < 65536) {
        w1b[idx] = (__bf16)w1[idx];                       // [d][j]
        int j = idx >> 7, d = idx & 127;
        w1Tb[idx] = (__bf16)w1[(size_t)d * DHID_ + j];    // [j][d]
        w2b[idx] = (__bf16)w2[idx];                       // [j][d]
        int d2 = idx >> 9, j2 = idx & 511;
        w2Tb[idx] = (__bf16)w2[(size_t)j2 * DH_ + d2];    // [d][j]
    }
    int n = idx >> 9, k = idx & 511;                      // WT[n][k] = W[k][n]
    WqT[idx] = (__bf16)Wq[(size_t)k * 512 + n];
    WkT[idx] = (__bf16)Wk[(size_t)k * 512 + n];
    WvT[idx] = (__bf16)Wv[(size_t)k * 512 + n];
    WcT[idx] = (__bf16)Wc[(size_t)k * 512 + n];
}

// ---------------------------------------------------------------- projections q/k/v
__global__ __launch_bounds__(256, 4) void proj_kernel(
    const __bf16* __restrict__ xsb, const __bf16* __restrict__ xrb,
    const __bf16* __restrict__ WqT, const __bf16* __restrict__ WkT,
    const __bf16* __restrict__ WvT,
    float* __restrict__ qb, float* __restrict__ kb, float* __restrict__ vb)
{
    const int z = blockIdx.z;
    const __bf16* A = (z == 0) ? xrb : xsb;
    const __bf16* WT = (z == 0) ? WqT : (z == 1 ? WkT : WvT);
    float* out = (z == 0) ? qb : (z == 1 ? kb : vb);
    const int t = threadIdx.x;
    const int wave = t >> 6, lane = t & 63;
    const int lrow = lane & 15, lgrp = lane >> 4;
    const int c0 = blockIdx.x * 64 + wave * 16;
    const int col0 = blockIdx.y * 64;
    f32x4 acc[4];
#pragma unroll
    for (int i = 0; i < 4; ++i) acc[i] = (f32x4)0.f;
    const __bf16* ar = A + (size_t)(c0 + lrow) * 512;
#pragma unroll 4
    for (int k0 = 0; k0 < 512; k0 += 32) {
        bf16x8 av = ld8(ar + k0 + lgrp * 8);
#pragma unroll
        for (int ct = 0; ct < 4; ++ct) {
            bf16x8 bv = ld8(WT + (size_t)(col0 + ct * 16 + lrow) * 512 + k0 + lgrp * 8);
            acc[ct] = MFMA(av, bv, acc[ct]);
        }
    }
#pragma unroll
    for (int ct = 0; ct < 4; ++ct)
#pragma unroll
        for (int r = 0; r < 4; ++r) {
            int row = c0 + lgrp * 4 + r, col = col0 + ct * 16 + lrow;
            int b = row >> 11, n = row & 2047, h = col >> 7, d = col & 127;
            out[((((size_t)(b * H_ + h) * NC_ + (n >> 6)) * CH_) + (n & 63)) * DH_ + d] = acc[ct][r];
        }
}

// ---------------------------------------------------------------- final combine GEMM
__global__ __launch_bounds__(256, 4) void gemm_out(
    const __bf16* __restrict__ A, const __bf16* __restrict__ WT, float* __restrict__ out)
{
    const int t = threadIdx.x;
    const int wave = t >> 6, lane = t & 63;
    const int lrow = lane & 15, lgrp = lane >> 4;
    const int c0 = blockIdx.x * 64 + wave * 16;
    const int col0 = blockIdx.y * 64;
    f32x4 acc[4];
#pragma unroll
    for (int i = 0; i < 4; ++i) acc[i] = (f32x4)0.f;
    const __bf16* ar = A + (size_t)(c0 + lrow) * 512;
#pragma unroll 4
    for (int k0 = 0; k0 < 512; k0 += 32) {
        bf16x8 av = ld8(ar + k0 + lgrp * 8);
#pragma unroll
        for (int ct = 0; ct < 4; ++ct) {
            bf16x8 bv = ld8(WT + (size_t)(col0 + ct * 16 + lrow) * 512 + k0 + lgrp * 8);
            acc[ct] = MFMA(av, bv, acc[ct]);
        }
    }
#pragma unroll
    for (int ct = 0; ct < 4; ++ct)
#pragma unroll
        for (int r = 0; r < 4; ++r) {
            int row = c0 + lgrp * 4 + r, col = col0 + ct * 16 + lrow;
            out[(size_t)row * 512 + col] = acc[ct][r];
        }
}

// ---------------------------------------------------------------- per-chunk surprise gradients (MFMA, 16 waves)
// monolithic (LDS-resident chunk data); dh pass eliminated algebraically:
//   dg[d] = sum_j w1[d][j] * G1[j][d] / g[d], G1 = dz^T @ h (the dw1 gradient)
__global__ __launch_bounds__(1024) void grad_kernel(
    const float* __restrict__ kbuf, const float* __restrict__ vbuf,
    const float* __restrict__ lrbuf, const float* __restrict__ memg,
    const __bf16* __restrict__ w1b, const __bf16* __restrict__ w1Tb,
    const __bf16* __restrict__ w2b, const __bf16* __restrict__ w2Tb,
    float* __restrict__ sg, __bf16* __restrict__ sw1, __bf16* __restrict__ sw2)
{
    const int blk = blockIdx.x;
    const int t = threadIdx.x;
    const int w = t >> 6, lane = t & 63;
    const int lrow = lane & 15, lgrp = lane >> 4;
    const int bh = blk >> 5, nc = blk & 31;
    const float* kc = kbuf + (size_t)blk * (CH_ * DH_);
    const float* vc = vbuf + (size_t)blk * (CH_ * DH_);
    const float* lrp = lrbuf + (size_t)bh * N_ + nc * CH_;
    __bf16* sw1_blk = sw1 + (size_t)blk * (DHID_ * DH_);
    __bf16* sw2_blk = sw2 + (size_t)blk * (DHID_ * DH_);

    __shared__ __bf16 h_s[64][136];
    __shared__ __bf16 e_s[64][136];
    __shared__ __bf16 a_s[64][136];
    __shared__ __bf16 hT_s[128][72];
    __shared__ __bf16 eT_s[128][72];
    __shared__ __bf16 aT_s[128][72];
    __shared__ __bf16 dzT_s[128][72];
    __shared__ float lr_s[64];
    __shared__ float g_s[128];
    __shared__ float part_dg[16][64];

    // ---- phase A: load k-chunk, rms, h = x*r*g ----
    if (t < 128) g_s[t] = memg[t];
    if (t < 64) lr_s[t] = lrp[t];
    {
        const int c = t >> 4, i8 = t & 15, d0 = i8 * 8;
        float xv[8];
        float ss = 0.f;
#pragma unroll
        for (int i = 0; i < 2; ++i) {
            float4 f = *(const float4*)(kc + (size_t)c * DH_ + d0 + i * 4);
            xv[i * 4 + 0] = f.x; xv[i * 4 + 1] = f.y; xv[i * 4 + 2] = f.z; xv[i * 4 + 3] = f.w;
            ss += f.x * f.x + f.y * f.y + f.z * f.z + f.w * f.w;
        }
        ss += __shfl_xor(ss, 1); ss += __shfl_xor(ss, 2);
        ss += __shfl_xor(ss, 4); ss += __shfl_xor(ss, 8);
        float r = rsqrtf(ss * (1.0f / DH_) + 1e-6f);
        __syncthreads();   // g_s visible
#pragma unroll
        for (int i = 0; i < 8; ++i)
            h_s[c][d0 + i] = (__bf16)(xv[i] * r * g_s[d0 + i]);
    }
    __syncthreads();
    {   // hT fill
        const int d = t >> 3, c0 = (t & 7) * 8;
#pragma unroll
        for (int i = 0; i < 8; ++i) hT_s[d][c0 + i] = h_s[c0 + i][d];
    }
    __syncthreads();

    // ---- pass 1: forward ---- wave -> (c-strip 16, d/j-quarter 32)
    const int cs = w & 3, dq = w >> 2;
    const int c0w = cs * 16, q0 = dq * 32;
    f32x4 yacc[2];
    yacc[0] = (f32x4)0.f; yacc[1] = (f32x4)0.f;

    bf16x8 w1r[8], w2r[8];
#pragma unroll
    for (int kt = 0; kt < 4; ++kt)
#pragma unroll
        for (int ct = 0; ct < 2; ++ct)
            w1r[kt * 2 + ct] = ld8(w1Tb + (size_t)(q0 + ct * 16 + lrow) * 128 + kt * 32 + lgrp * 8);

    for (int jt = 0; jt < 4; ++jt) {
        f32x4 zacc[2];
        zacc[0] = (f32x4)0.f; zacc[1] = (f32x4)0.f;
#pragma unroll
        for (int kt = 0; kt < 4; ++kt) {
            bf16x8 av = ld8(&h_s[c0w + lrow][kt * 32 + lgrp * 8]);
            zacc[0] = MFMA(av, w1r[kt * 2 + 0], zacc[0]);
            zacc[1] = MFMA(av, w1r[kt * 2 + 1], zacc[1]);
        }
        // prefetch this jt's w2 columns (used after barrier)
#pragma unroll
        for (int kt = 0; kt < 4; ++kt)
#pragma unroll
            for (int ct = 0; ct < 2; ++ct)
                w2r[kt * 2 + ct] = ld8(w2Tb + (size_t)(q0 + ct * 16 + lrow) * 512 + jt * 128 + kt * 32 + lgrp * 8);
#pragma unroll
        for (int ct = 0; ct < 2; ++ct)
#pragma unroll
            for (int r = 0; r < 4; ++r)
                a_s[c0w + lgrp * 4 + r][q0 + ct * 16 + lrow] = (__bf16)gelu_f(zacc[ct][r]);
        __syncthreads();
#pragma unroll
        for (int kt = 0; kt < 4; ++kt) {
            bf16x8 av = ld8(&a_s[c0w + lrow][kt * 32 + lgrp * 8]);
            yacc[0] = MFMA(av, w2r[kt * 2 + 0], yacc[0]);
            yacc[1] = MFMA(av, w2r[kt * 2 + 1], yacc[1]);
        }
        // prefetch next jt's w1 columns (used after barrier)
        if (jt < 3) {
#pragma unroll
            for (int kt = 0; kt < 4; ++kt)
#pragma unroll
                for (int ct = 0; ct < 2; ++ct)
                    w1r[kt * 2 + ct] = ld8(w1Tb + (size_t)((jt + 1) * 128 + q0 + ct * 16 + lrow) * 128 + kt * 32 + lgrp * 8);
        }
        __syncthreads();
    }
    // e = lr*2/DH*(y + x - v)
#pragma unroll
    for (int ct = 0; ct < 2; ++ct)
#pragma unroll
        for (int r = 0; r < 4; ++r) {
            int c = c0w + lgrp * 4 + r, d = q0 + ct * 16 + lrow;
            float xvv = kc[(size_t)c * DH_ + d];
            float vvv = vc[(size_t)c * DH_ + d];
            float e = lr_s[c] * (2.0f / DH_) * (yacc[ct][r] + xvv - vvv);
            e_s[c][d] = (__bf16)e;
            eT_s[d][c] = (__bf16)e;
        }
    __syncthreads();

    // ---- pass 2: backward ---- wave -> (j/d-strip 16, c/d/j-half)
    const int js = w & 7, chh = w >> 3;
    float dgacc[4] = {0.f, 0.f, 0.f, 0.f};

    bf16x8 azr[4], adr[4];
#pragma unroll
    for (int kt = 0; kt < 4; ++kt) {
        azr[kt] = ld8(w1Tb + (size_t)(js * 16 + lrow) * 128 + kt * 32 + lgrp * 8);
        adr[kt] = ld8(w2b + (size_t)(js * 16 + lrow) * 128 + kt * 32 + lgrp * 8);
    }

    for (int jt = 0; jt < 4; ++jt) {
        // zT[j-strip, c-half] = w1T @ hT ; daT = w2 @ eT
        f32x4 ztacc[2], dtacc[2];
        ztacc[0] = (f32x4)0.f; ztacc[1] = (f32x4)0.f;
        dtacc[0] = (f32x4)0.f; dtacc[1] = (f32x4)0.f;
#pragma unroll
        for (int kt = 0; kt < 4; ++kt) {
#pragma unroll
            for (int ct = 0; ct < 2; ++ct) {
                bf16x8 bvh = ld8(&h_s[chh * 32 + ct * 16 + lrow][kt * 32 + lgrp * 8]);
                bf16x8 bve = ld8(&e_s[chh * 32 + ct * 16 + lrow][kt * 32 + lgrp * 8]);
                ztacc[ct] = MFMA(azr[kt], bvh, ztacc[ct]);
                dtacc[ct] = MFMA(adr[kt], bve, dtacc[ct]);
            }
        }
#pragma unroll
        for (int ct = 0; ct < 2; ++ct)
#pragma unroll
            for (int r = 0; r < 4; ++r) {
                int jl = js * 16 + lgrp * 4 + r, c = chh * 32 + ct * 16 + lrow;
                float gf, gg;
                gelu_fg(ztacc[ct][r], gf, gg);
                aT_s[jl][c] = (__bf16)gf;
                dzT_s[jl][c] = (__bf16)(dtacc[ct][r] * gg);
            }
        __syncthreads();
        // dw1T[j-strip, d-half] = dzT @ hT ; fused dg contribution
        {
            f32x4 wacc[4];
#pragma unroll
            for (int i = 0; i < 4; ++i) wacc[i] = (f32x4)0.f;
#pragma unroll
            for (int kt = 0; kt < 2; ++kt) {
                bf16x8 av = ld8(&dzT_s[js * 16 + lrow][kt * 32 + lgrp * 8]);
#pragma unroll
                for (int ct = 0; ct < 4; ++ct) {
                    bf16x8 bv = ld8(&hT_s[chh * 64 + ct * 16 + lrow][kt * 32 + lgrp * 8]);
                    wacc[ct] = MFMA(av, bv, wacc[ct]);
                }
            }
#pragma unroll
            for (int ct = 0; ct < 4; ++ct) {
                int d = chh * 64 + ct * 16 + lrow;
#pragma unroll
                for (int r = 0; r < 4; ++r) {
                    int jg = jt * 128 + js * 16 + lgrp * 4 + r;
                    sw1_blk[(size_t)jg * 128 + d] = (__bf16)(-wacc[ct][r]);
                    // dg[d] -= w1[d][jg] * G1[jg][d]  (w1Tb[jg][d] = w1[d][jg], L2-hot)
                    dgacc[ct] -= (float)w1Tb[(size_t)jg * 128 + d] * wacc[ct][r];
                }
            }
        }
        // dw2T[d-strip, j-half] = eT @ a
        {
            f32x4 wacc[4];
#pragma unroll
            for (int i = 0; i < 4; ++i) wacc[i] = (f32x4)0.f;
#pragma unroll
            for (int kt = 0; kt < 2; ++kt) {
                bf16x8 av = ld8(&eT_s[js * 16 + lrow][kt * 32 + lgrp * 8]);
#pragma unroll
                for (int ct = 0; ct < 4; ++ct) {
                    bf16x8 bv = ld8(&aT_s[chh * 64 + ct * 16 + lrow][kt * 32 + lgrp * 8]);
                    wacc[ct] = MFMA(av, bv, wacc[ct]);
                }
            }
#pragma unroll
            for (int ct = 0; ct < 4; ++ct)
#pragma unroll
                for (int r = 0; r < 4; ++r) {
                    int d = js * 16 + lgrp * 4 + r, jg = jt * 128 + chh * 64 + ct * 16 + lrow;
                    sw2_blk[(size_t)d * 512 + jg] = (__bf16)(-wacc[ct][r]);
                }
        }
        // prefetch next jt's azr/adr (used after barrier)
        if (jt < 3) {
#pragma unroll
            for (int kt = 0; kt < 4; ++kt) {
                azr[kt] = ld8(w1Tb + (size_t)((jt + 1) * 128 + js * 16 + lrow) * 128 + kt * 32 + lgrp * 8);
                adr[kt] = ld8(w2b + (size_t)((jt + 1) * 128 + js * 16 + lrow) * 128 + kt * 32 + lgrp * 8);
            }
        }
        __syncthreads();
    }
    // dg reduce: xor over lgrp, then over the 8 js-waves of each chh group
#pragma unroll
    for (int ct = 0; ct < 4; ++ct) {
        dgacc[ct] += __shfl_xor(dgacc[ct], 16);
        dgacc[ct] += __shfl_xor(dgacc[ct], 32);
    }
    if (lane < 16) {
#pragma unroll
        for (int ct = 0; ct < 4; ++ct) part_dg[w][ct * 16 + lane] = dgacc[ct];
    }
    __syncthreads();
    if (t < 128) {
        int grp = t >> 6;     // d-half -> chh group
        float s = 0.f;
#pragma unroll
        for (int j = 0; j < 8; ++j) s += part_dg[grp * 8 + j][t & 63];
        sg[(size_t)blk * DH_ + t] = s / g_s[t];
    }
}

// ---------------------------------------------------------------- all scans, one launch (bf16x8 vectorized)
__global__ __launch_bounds__(256) void scan_all(
    __bf16* __restrict__ sw1, const __bf16* __restrict__ w1T,
    __bf16* __restrict__ sw2, const __bf16* __restrict__ w2T,
    float* __restrict__ sgb, const float* __restrict__ memg,
    const float* __restrict__ beta, const float* __restrict__ alpha)
{
    const int bi = blockIdx.x, t = threadIdx.x;
    if (bi < 512) {
        __bf16* buf = (bi < 256) ? sw1 : sw2;
        const __bf16* init = (bi < 256) ? w1T : w2T;
        int idx = (bi & 255) * 256 + t;          // 0..65535
        int bh = idx >> 13, e8 = idx & 8191;
        size_t off = (size_t)e8 * 8;
        const float* bp = beta + bh * NC_;
        const float* ap = alpha + bh * NC_;
        __bf16* base = buf + (size_t)bh * NC_ * 65536 + off;
        bf16x8 iv = *(const bf16x8*)(init + off);
        float m[8], wv[8];
#pragma unroll
        for (int k = 0; k < 8; ++k) { m[k] = 0.f; wv[k] = (float)iv[k]; }
        for (int ci = 0; ci < NC_; ++ci) {
            bf16x8 s = *(const bf16x8*)(base + (size_t)ci * 65536);
            float bb = bp[ci], aa = ap[ci];
            bf16x8 o;
#pragma unroll
            for (int k = 0; k < 8; ++k) {
                o[k] = (__bf16)wv[k];
                m[k] = fmaf(bb, m[k], (float)s[k]);
                wv[k] = fmaf(aa, wv[k], m[k]);
            }
            *(bf16x8*)(base + (size_t)ci * 65536) = o;
        }
    } else {
        int idx = (bi - 512) * 256 + t;   // < 1024
        int bh = idx >> 7, el = idx & 127;
        float wv = memg[el], m = 0.f;
        const float* bp = beta + bh * NC_;
        const float* ap = alpha + bh * NC_;
        float* base = sgb + ((size_t)bh * NC_) * 128 + el;
        for (int ci = 0; ci < NC_; ++ci) {
            float s = base[(size_t)ci * 128];
            base[(size_t)ci * 128] = wv;
            m = fmaf(bp[ci], m, s);
            wv = fmaf(ap[ci], wv, m);
        }
    }
}

// ---------------------------------------------------------------- retrieval (MFMA forward, 8 waves) + gate
__global__ __launch_bounds__(512, 4) void retrieve_kernel(
    const float* __restrict__ qbuf, const float* __restrict__ gatebuf,
    const float* __restrict__ sg, const __bf16* __restrict__ sw1,
    const __bf16* __restrict__ sw2, __bf16* __restrict__ retgb)
{
    const int blk = blockIdx.x;
    const int t = threadIdx.x;
    const int w = t >> 6, lane = t & 63;
    const int lrow = lane & 15, lgrp = lane >> 4;
    const int bh = blk >> 5, nc = blk & 31;
    const float* qc = qbuf + (size_t)blk * (CH_ * DH_);
    const __bf16* w1p = sw1 + (size_t)blk * (DHID_ * DH_);
    const __bf16* w2p = sw2 + (size_t)blk * (DHID_ * DH_);
    const float* gp = sg + (size_t)blk * DH_;

    __shared__ __bf16 h_s[64][136];
    __shared__ __bf16 a_s[64][136];
    __shared__ float g_s[128];

    if (t < 128) g_s[t] = gp[t];
    {
        const int c = t >> 3, dblk = t & 7, d0 = dblk * 16;
        float xv[16];
        float ss = 0.f;
#pragma unroll
        for (int i = 0; i < 4; ++i) {
            float4 f = *(const float4*)(qc + (size_t)c * DH_ + d0 + i * 4);
            xv[i * 4 + 0] = f.x; xv[i * 4 + 1] = f.y; xv[i * 4 + 2] = f.z; xv[i * 4 + 3] = f.w;
            ss += f.x * f.x + f.y * f.y + f.z * f.z + f.w * f.w;
        }
        ss += __shfl_xor(ss, 1); ss += __shfl_xor(ss, 2); ss += __shfl_xor(ss, 4);
        float r = rsqrtf(ss * (1.0f / DH_) + 1e-6f);
        __syncthreads();   // g_s visible
#pragma unroll
        for (int i = 0; i < 16; ++i)
            h_s[c][d0 + i] = (__bf16)(xv[i] * r * g_s[d0 + i]);
    }
    __syncthreads();

    const int cs = w & 3, dh2 = w >> 2;
    const int c0w = cs * 16, d0w = dh2 * 64;
    f32x4 yacc[4];
#pragma unroll
    for (int i = 0; i < 4; ++i) yacc[i] = (f32x4)0.f;

    for (int jt = 0; jt < 4; ++jt) {
        f32x4 zacc[4];
#pragma unroll
        for (int i = 0; i < 4; ++i) zacc[i] = (f32x4)0.f;
#pragma unroll
        for (int kt = 0; kt < 4; ++kt) {
            bf16x8 av = ld8(&h_s[c0w + lrow][kt * 32 + lgrp * 8]);
#pragma unroll
            for (int ct = 0; ct < 4; ++ct) {
                int j = jt * 128 + d0w + ct * 16 + lrow;
                bf16x8 bv = ld8(w1p + (size_t)j * 128 + kt * 32 + lgrp * 8);
                zacc[ct] = MFMA(av, bv, zacc[ct]);
            }
        }
#pragma unroll
        for (int ct = 0; ct < 4; ++ct)
#pragma unroll
            for (int r = 0; r < 4; ++r)
                a_s[c0w + lgrp * 4 + r][d0w + ct * 16 + lrow] = (__bf16)gelu_f(zacc[ct][r]);
        __syncthreads();
#pragma unroll
        for (int kt = 0; kt < 4; ++kt) {
            bf16x8 av = ld8(&a_s[c0w + lrow][kt * 32 + lgrp * 8]);
#pragma unroll
            for (int ct = 0; ct < 4; ++ct) {
                int d = d0w + ct * 16 + lrow;
                bf16x8 bv = ld8(w2p + (size_t)d * 512 + jt * 128 + kt * 32 + lgrp * 8);
                yacc[ct] = MFMA(av, bv, yacc[ct]);
            }
        }
        __syncthreads();
    }
    const int b = bh >> 2, hh = bh & 3;
#pragma unroll
    for (int ct = 0; ct < 4; ++ct)
#pragma unroll
        for (int r = 0; r < 4; ++r) {
            int c = c0w + lgrp * 4 + r, d = d0w + ct * 16 + lrow;
            int n = nc * CH_ + c;
            float q = qc[(size_t)c * DH_ + d];
            float gv = gatebuf[(size_t)bh * N_ + n];
            retgb[((size_t)(b * N_ + n)) * 512 + hh * 128 + d] = (__bf16)((yacc[ct][r] + q) * gv);
        }
}

// ---------------------------------------------------------------- launch
extern "C" void kernel_launch(void* const* d_in, const int* in_sizes, int n_in,
                              void* d_out, int out_size, void* d_ws, size_t ws_size,
                              hipStream_t stream) {
    const float* seq     = (const float*)d_in[0];
    const float* g_store = (const float*)d_in[1];
    const float* g_retr  = (const float*)d_in[2];
    const float* Wq = (const float*)d_in[3];
    const float* Wk = (const float*)d_in[4];
    const float* Wv = (const float*)d_in[5];
    const float* Wa = (const float*)d_in[6];
    const float* ba = (const float*)d_in[7];
    const float* Wm = (const float*)d_in[8];
    const float* Wd = (const float*)d_in[9];
    const float* bd = (const float*)d_in[10];
    const float* Wg = (const float*)d_in[11];
    const float* Wc = (const float*)d_in[12];
    const float* memg = (const float*)d_in[13];
    const float* w1 = (const float*)d_in[14];
    const float* w2 = (const float*)d_in[15];
    float* out = (float*)d_out;

    float* p = (float*)d_ws;
    float* xs = p;     p += (size_t)B_ * N_ * DIM_;
    float* kb = p;     p += (size_t)B_ * N_ * DIM_;
    float* vb = p;     p += (size_t)B_ * N_ * DIM_;
    float* qb = p;     p += (size_t)B_ * N_ * DIM_;
    float* lrb = p;    p += (size_t)BH_ * N_;
    float* gateb = p;  p += (size_t)BH_ * N_;
    float* beta = p;   p += BH_ * NC_;
    float* alpha = p;  p += BH_ * NC_;
    float* sgb = p;    p += (size_t)BH_ * NC_ * DH_;

    __bf16* bp_ = (__bf16*)p;
    __bf16* xsb = bp_;  bp_ += (size_t)B_ * N_ * DIM_;
    __bf16* xrb = bp_;  bp_ += (size_t)B_ * N_ * DIM_;
    __bf16* retgb = bp_; bp_ += (size_t)B_ * N_ * DIM_;
    __bf16* w1b = bp_;  bp_ += DH_ * DHID_;
    __bf16* w1Tb = bp_; bp_ += DH_ * DHID_;
    __bf16* w2b = bp_;  bp_ += DH_ * DHID_;
    __bf16* w2Tb = bp_; bp_ += DH_ * DHID_;
    __bf16* WqT = bp_;  bp_ += DIM_ * DIM_;
    __bf16* WkT = bp_;  bp_ += DIM_ * DIM_;
    __bf16* WvT = bp_;  bp_ += DIM_ * DIM_;
    __bf16* WcT = bp_;  bp_ += DIM_ * DIM_;
    __bf16* sw1b = bp_; bp_ += (size_t)BH_ * NC_ * DH_ * DHID_;
    __bf16* sw2b = bp_; bp_ += (size_t)BH_ * NC_ * DH_ * DHID_;

    rms_kernel<<<B_ * N_, 256, 0, stream>>>(seq, g_store, g_retr, Wa, ba, Wg,
                                            xs, xsb, xrb, lrb, gateb);
    ba_kernel<<<B_ * NC_, 256, 0, stream>>>(xs, Wm, Wd, bd, beta, alpha);
    prep_kernel<<<1024, 256, 0, stream>>>(w1, w2, Wq, Wk, Wv, Wc,
                                          w1b, w1Tb, w2b, w2Tb, WqT, WkT, WvT, WcT);
    proj_kernel<<<dim3(64, 8, 3), 256, 0, stream>>>(xsb, xrb, WqT, WkT, WvT, qb, kb, vb);
    grad_kernel<<<BH_ * NC_, 1024, 0, stream>>>(kb, vb, lrb, memg, w1b, w1Tb, w2b, w2Tb,
                                                sgb, sw1b, sw2b);
    scan_all<<<516, 256, 0, stream>>>(sw1b, w1Tb, sw2b, w2Tb, sgb, memg, beta, alpha);
    retrieve_kernel<<<BH_ * NC_, 512, 0, stream>>>(qb, gateb, sgb, sw1b, sw2b, retgb);
    gemm_out<<<dim3(64, 8), 256, 0, stream>>>(retgb, WcT, out);
}